// Round 1
// baseline (323.199 us; speedup 1.0000x reference)
//
#include <hip/hip_runtime.h>
#include <hip/hip_bf16.h>
#include <math.h>

#define NN 50000
#define NE 800000
#define HD 128

typedef unsigned int u32;
typedef unsigned short u16;

__device__ __forceinline__ u16 f2bf(float f) {
    u32 u = __float_as_uint(f);
    u32 r = u + 0x7FFFu + ((u >> 16) & 1u);   // round-to-nearest-even
    return (u16)(r >> 16);
}
__device__ __forceinline__ float bf2f(u16 h) {
    return __uint_as_float(((u32)h) << 16);
}
__device__ __forceinline__ void unpack8(uint4 p, float* f) {
    f[0] = __uint_as_float(p.x << 16); f[1] = __uint_as_float(p.x & 0xFFFF0000u);
    f[2] = __uint_as_float(p.y << 16); f[3] = __uint_as_float(p.y & 0xFFFF0000u);
    f[4] = __uint_as_float(p.z << 16); f[5] = __uint_as_float(p.z & 0xFFFF0000u);
    f[6] = __uint_as_float(p.w << 16); f[7] = __uint_as_float(p.w & 0xFFFF0000u);
}

// ---- prep: zero counters, convert x -> bf16, W -> bf16 transposed ----
__global__ void prep_kernel(const float* __restrict__ x, const float* __restrict__ W,
                            u16* __restrict__ xh, u16* __restrict__ wt,
                            u32* __restrict__ counts, u32* __restrict__ cursor,
                            float* __restrict__ colsum, float* __restrict__ colsq) {
    int idx = blockIdx.x * blockDim.x + threadIdx.x;   // exactly NN*HD/4 threads
    {
        const float4 v = reinterpret_cast<const float4*>(x)[idx];
        u32 lo = (u32)f2bf(v.x) | ((u32)f2bf(v.y) << 16);
        u32 hi = (u32)f2bf(v.z) | ((u32)f2bf(v.w) << 16);
        reinterpret_cast<uint2*>(xh)[idx] = make_uint2(lo, hi);
    }
    if (idx < NN) { counts[idx] = 0u; cursor[idx] = 0u; }
    if (idx < HD * HD) {
        int k = idx >> 7, c = idx & 127;
        wt[c * HD + k] = f2bf(W[idx]);     // wt[c][k] = W[k][c]
    }
    if (idx < HD) { colsum[idx] = 0.f; colsq[idx] = 0.f; }
}

// ---- histogram of in-degrees ----
__global__ void hist_kernel(const int* __restrict__ dst, u32* __restrict__ counts) {
    int e = blockIdx.x * blockDim.x + threadIdx.x;
    if (e < NE) atomicAdd(&counts[dst[e]], 1u);
}

// ---- single-block exclusive scan -> rowptr, plus dinv = rsqrt(deg+1) ----
__global__ void scan_kernel(const u32* __restrict__ counts, u32* __restrict__ rowptr,
                            float* __restrict__ dinv) {
    __shared__ u32 ls[1024];
    const int tid = threadIdx.x;
    const int CH = (NN + 1023) / 1024;  // 49
    int base = tid * CH;
    u32 sum = 0;
    for (int j = 0; j < CH; ++j) { int i = base + j; if (i < NN) sum += counts[i]; }
    ls[tid] = sum;
    __syncthreads();
    for (int off = 1; off < 1024; off <<= 1) {
        u32 v = (tid >= off) ? ls[tid - off] : 0u;
        __syncthreads();
        ls[tid] += v;
        __syncthreads();
    }
    u32 run = ls[tid] - sum;  // exclusive offset
    for (int j = 0; j < CH; ++j) {
        int i = base + j;
        if (i < NN) {
            rowptr[i] = run;
            u32 c = counts[i];
            run += c;
            dinv[i] = rsqrtf((float)(c + 1u));   // +1 self loop; always > 0
        }
    }
    if (tid == 0) rowptr[NN] = NE;
}

// ---- scatter edge sources into CSR ----
__global__ void scatter_kernel(const int* __restrict__ src, const int* __restrict__ dst,
                               const u32* __restrict__ rowptr, u32* __restrict__ cursor,
                               u32* __restrict__ srclist) {
    int e = blockIdx.x * blockDim.x + threadIdx.x;
    if (e < NE) {
        int d = dst[e];
        u32 r = atomicAdd(&cursor[d], 1u);
        srclist[rowptr[d] + r] = (u32)src[e];
    }
}

// ---- aggregation: one wave per node; 4 edge slots x 16 lanes x 8 features ----
__global__ __launch_bounds__(256) void agg_kernel(
        const u16* __restrict__ xh, const u32* __restrict__ rowptr,
        const u32* __restrict__ srclist, const float* __restrict__ dinv,
        u16* __restrict__ aggX) {
    int wid = (blockIdx.x * blockDim.x + threadIdx.x) >> 6;
    if (wid >= NN) return;
    const int lane = threadIdx.x & 63;
    const int eq = lane >> 4;      // edge slot 0..3
    const int fl = lane & 15;      // feature slice (8 bf16 = 16B)
    const int v = wid;
    const float dv = dinv[v];
    float acc[8];
    {
        uint4 sv = reinterpret_cast<const uint4*>(xh + (size_t)v * HD)[fl];
        float f[8]; unpack8(sv, f);
        float s = (eq == 0) ? dv : 0.f;       // self-loop term dv^2*x[v] (dv applied again at end)
        #pragma unroll
        for (int j = 0; j < 8; ++j) acc[j] = s * f[j];
    }
    const u32 rs = rowptr[v], re = rowptr[v + 1];
    for (u32 i = rs + eq; i < re; i += 4) {
        u32 u = srclist[i];
        float du = dinv[u];
        uint4 mu = reinterpret_cast<const uint4*>(xh + (size_t)u * HD)[fl];
        float f[8]; unpack8(mu, f);
        #pragma unroll
        for (int j = 0; j < 8; ++j) acc[j] = fmaf(du, f[j], acc[j]);
    }
    #pragma unroll
    for (int j = 0; j < 8; ++j) {
        acc[j] += __shfl_xor(acc[j], 16, 64);
        acc[j] += __shfl_xor(acc[j], 32, 64);
    }
    if (eq == 0) {
        u32 w[4];
        #pragma unroll
        for (int q = 0; q < 4; ++q) {
            w[q] = (u32)f2bf(dv * acc[2 * q]) | ((u32)f2bf(dv * acc[2 * q + 1]) << 16);
        }
        reinterpret_cast<uint4*>(aggX + (size_t)v * HD)[fl] =
            make_uint4(w[0], w[1], w[2], w[3]);
    }
}

// ---- GEMM: agg = aggX @ W + b (fp32 VALU, bf16 operands), fused BN stats ----
__global__ __launch_bounds__(256) void gemm_kernel(
        const u16* __restrict__ aggX, const u16* __restrict__ wt,
        const float* __restrict__ bias,
        u16* __restrict__ agg, float* __restrict__ colsum, float* __restrict__ colsq) {
    __shared__ u16 Ws[128 * 132];     // wt staged, stride 132 -> 2-way max bank aliasing
    __shared__ u16 xs[32 * 128];
    __shared__ float cs_l[128];
    __shared__ float cq_l[128];
    const int tid = threadIdx.x;
    const int rbase = blockIdx.x * 32;
    if (tid < 128) { cs_l[tid] = 0.f; cq_l[tid] = 0.f; }
    for (int q = tid; q < 128 * 32; q += 256) {          // 4096 uint2 of W
        int c = q >> 5, kq = q & 31;
        uint2 w = reinterpret_cast<const uint2*>(wt)[q];
        *reinterpret_cast<uint2*>(&Ws[c * 132 + kq * 4]) = w;
    }
    for (int q = tid; q < 32 * 32; q += 256) {           // 1024 uint2 of x tile
        int rr = q >> 5, kq = q & 31;
        int row = rbase + rr;
        uint2 w = (row < NN) ? reinterpret_cast<const uint2*>(aggX + (size_t)row * HD)[kq]
                             : make_uint2(0u, 0u);
        *reinterpret_cast<uint2*>(&xs[rr * 128 + kq * 4]) = w;
    }
    __syncthreads();
    const int rg = tid >> 5, cg = tid & 31;   // rows rg+8i, cols cg+32j
    float acc[4][4] = {};
    for (int k = 0; k < 128; k += 4) {
        float xf[4][4], wf[4][4];
        #pragma unroll
        for (int i = 0; i < 4; ++i) {
            uint2 a = *reinterpret_cast<const uint2*>(&xs[(rg + 8 * i) * 128 + k]);
            xf[i][0] = __uint_as_float(a.x << 16); xf[i][1] = __uint_as_float(a.x & 0xFFFF0000u);
            xf[i][2] = __uint_as_float(a.y << 16); xf[i][3] = __uint_as_float(a.y & 0xFFFF0000u);
        }
        #pragma unroll
        for (int j = 0; j < 4; ++j) {
            uint2 w = *reinterpret_cast<const uint2*>(&Ws[(cg + 32 * j) * 132 + k]);
            wf[j][0] = __uint_as_float(w.x << 16); wf[j][1] = __uint_as_float(w.x & 0xFFFF0000u);
            wf[j][2] = __uint_as_float(w.y << 16); wf[j][3] = __uint_as_float(w.y & 0xFFFF0000u);
        }
        #pragma unroll
        for (int i = 0; i < 4; ++i)
            #pragma unroll
            for (int j = 0; j < 4; ++j)
                #pragma unroll
                for (int kk = 0; kk < 4; ++kk)
                    acc[i][j] = fmaf(xf[i][kk], wf[j][kk], acc[i][j]);
    }
    float bj[4];
    #pragma unroll
    for (int j = 0; j < 4; ++j) bj[j] = bias[cg + 32 * j];
    float cp[4] = {0.f, 0.f, 0.f, 0.f}, cq[4] = {0.f, 0.f, 0.f, 0.f};
    #pragma unroll
    for (int i = 0; i < 4; ++i) {
        int row = rbase + rg + 8 * i;
        if (row < NN) {
            #pragma unroll
            for (int j = 0; j < 4; ++j) {
                float vv = acc[i][j] + bj[j];
                agg[(size_t)row * HD + cg + 32 * j] = f2bf(vv);
                cp[j] += vv;
                cq[j] += vv * vv;
            }
        }
    }
    #pragma unroll
    for (int j = 0; j < 4; ++j) {
        atomicAdd(&cs_l[cg + 32 * j], cp[j]);
        atomicAdd(&cq_l[cg + 32 * j], cq[j]);
    }
    __syncthreads();
    if (tid < 128) {
        atomicAdd(&colsum[tid], cs_l[tid]);
        atomicAdd(&colsq[tid], cq_l[tid]);
    }
}

// ---- BN stats finalize ----
__global__ void stats_kernel(const float* __restrict__ colsum, const float* __restrict__ colsq,
                             const float* __restrict__ gamma, const float* __restrict__ beta,
                             float* __restrict__ sc, float* __restrict__ sh) {
    int c = threadIdx.x;
    float m = colsum[c] * (1.f / NN);
    float var = colsq[c] * (1.f / NN) - m * m;
    float inv = rsqrtf(var + 1e-5f);
    float s = gamma[c] * inv;
    sc[c] = s;
    sh[c] = beta[c] - m * s;
}

// ---- normalize + ReLU + residual ----
__global__ void final_kernel(const u16* __restrict__ agg, const float* __restrict__ last_x,
                             const float* __restrict__ sc, const float* __restrict__ sh,
                             float* __restrict__ out) {
    int idx = blockIdx.x * blockDim.x + threadIdx.x;   // NN*HD/4 threads
    int c0 = (idx * 4) & 127;
    uint2 a = reinterpret_cast<const uint2*>(agg)[idx];
    float4 lx = reinterpret_cast<const float4*>(last_x)[idx];
    float f0 = __uint_as_float(a.x << 16), f1 = __uint_as_float(a.x & 0xFFFF0000u);
    float f2 = __uint_as_float(a.y << 16), f3 = __uint_as_float(a.y & 0xFFFF0000u);
    float4 o;
    o.x = fmaxf(fmaf(f0, sc[c0 + 0], sh[c0 + 0]), 0.f) + lx.x;
    o.y = fmaxf(fmaf(f1, sc[c0 + 1], sh[c0 + 1]), 0.f) + lx.y;
    o.z = fmaxf(fmaf(f2, sc[c0 + 2], sh[c0 + 2]), 0.f) + lx.z;
    o.w = fmaxf(fmaf(f3, sc[c0 + 3], sh[c0 + 3]), 0.f) + lx.w;
    reinterpret_cast<float4*>(out)[idx] = o;
}

extern "C" void kernel_launch(void* const* d_in, const int* in_sizes, int n_in,
                              void* d_out, int out_size, void* d_ws, size_t ws_size,
                              hipStream_t stream) {
    const float* x      = (const float*)d_in[0];
    const float* last_x = (const float*)d_in[1];
    const int*   edge   = (const int*)d_in[2];   // [2][NE]
    const float* W      = (const float*)d_in[3];
    const float* bias   = (const float*)d_in[4];
    const float* gamma  = (const float*)d_in[5];
    const float* beta   = (const float*)d_in[6];
    float* out = (float*)d_out;

    char* ws = (char*)d_ws;
    size_t p = 0;
    auto take = [&](size_t bytes) { size_t r = p; p += (bytes + 255) & ~255ULL; return r; };
    u32*   counts  = (u32*)(ws + take((size_t)NN * 4));
    u32*   rowptr  = (u32*)(ws + take((size_t)(NN + 1) * 4));
    u32*   cursor  = (u32*)(ws + take((size_t)NN * 4));
    u32*   srclist = (u32*)(ws + take((size_t)NE * 4));
    float* dinv    = (float*)(ws + take((size_t)NN * 4));
    u16*   xh      = (u16*)(ws + take((size_t)NN * HD * 2));
    u16*   aggX    = (u16*)(ws + take((size_t)NN * HD * 2));
    u16*   aggb    = (u16*)(ws + take((size_t)NN * HD * 2));
    u16*   wt      = (u16*)(ws + take((size_t)HD * HD * 2));
    float* colsum  = (float*)(ws + take((size_t)HD * 4));
    float* colsq   = (float*)(ws + take((size_t)HD * 4));
    float* sc      = (float*)(ws + take((size_t)HD * 4));
    float* sh      = (float*)(ws + take((size_t)HD * 4));

    const int* srcp = edge;
    const int* dstp = edge + NE;

    prep_kernel<<<(NN * HD / 4) / 256, 256, 0, stream>>>(x, W, xh, wt, counts, cursor, colsum, colsq);
    hist_kernel<<<(NE + 255) / 256, 256, 0, stream>>>(dstp, counts);
    scan_kernel<<<1, 1024, 0, stream>>>(counts, rowptr, dinv);
    scatter_kernel<<<(NE + 255) / 256, 256, 0, stream>>>(srcp, dstp, rowptr, cursor, srclist);
    agg_kernel<<<(NN + 3) / 4, 256, 0, stream>>>(xh, rowptr, srclist, dinv, aggX);
    gemm_kernel<<<(NN + 31) / 32, 256, 0, stream>>>(aggX, wt, bias, aggb, colsum, colsq);
    stats_kernel<<<1, HD, 0, stream>>>(colsum, colsq, gamma, beta, sc, sh);
    final_kernel<<<(NN * HD / 4) / 256, 256, 0, stream>>>(aggb, last_x, sc, sh, out);
}

// Round 2
// 204.494 us; speedup vs baseline: 1.5805x; 1.5805x over previous
//
#include <hip/hip_runtime.h>
#include <hip/hip_bf16.h>
#include <math.h>

#define NN 50000
#define NE 800000
#define HD 128
#define SCAN_ELEMS 1024                       // elements per scan block
#define NBLK ((NN + SCAN_ELEMS - 1) / SCAN_ELEMS)   // 49

typedef unsigned int u32;
typedef unsigned short u16;

__device__ __forceinline__ u16 f2bf(float f) {
    u32 u = __float_as_uint(f);
    u32 r = u + 0x7FFFu + ((u >> 16) & 1u);   // round-to-nearest-even
    return (u16)(r >> 16);
}
__device__ __forceinline__ void unpack8(uint4 p, float* f) {
    f[0] = __uint_as_float(p.x << 16); f[1] = __uint_as_float(p.x & 0xFFFF0000u);
    f[2] = __uint_as_float(p.y << 16); f[3] = __uint_as_float(p.y & 0xFFFF0000u);
    f[4] = __uint_as_float(p.z << 16); f[5] = __uint_as_float(p.z & 0xFFFF0000u);
    f[6] = __uint_as_float(p.w << 16); f[7] = __uint_as_float(p.w & 0xFFFF0000u);
}

// ---- prep: zero counters, convert x -> bf16, W -> bf16 transposed ----
__global__ void prep_kernel(const float* __restrict__ x, const float* __restrict__ W,
                            u16* __restrict__ xh, u16* __restrict__ wt,
                            u32* __restrict__ counts, u32* __restrict__ cursor,
                            float* __restrict__ colsum, float* __restrict__ colsq) {
    int idx = blockIdx.x * blockDim.x + threadIdx.x;   // exactly NN*HD/4 threads
    {
        const float4 v = reinterpret_cast<const float4*>(x)[idx];
        u32 lo = (u32)f2bf(v.x) | ((u32)f2bf(v.y) << 16);
        u32 hi = (u32)f2bf(v.z) | ((u32)f2bf(v.w) << 16);
        reinterpret_cast<uint2*>(xh)[idx] = make_uint2(lo, hi);
    }
    if (idx < NN) { counts[idx] = 0u; cursor[idx] = 0u; }
    if (idx < HD * HD) {
        int k = idx >> 7, c = idx & 127;
        wt[c * HD + k] = f2bf(W[idx]);     // wt[c][k] = W[k][c]
    }
    if (idx < HD) { colsum[idx] = 0.f; colsq[idx] = 0.f; }
}

// ---- histogram of in-degrees ----
__global__ void hist_kernel(const int* __restrict__ dst, u32* __restrict__ counts) {
    int e = blockIdx.x * blockDim.x + threadIdx.x;
    if (e < NE) atomicAdd(&counts[dst[e]], 1u);
}

// ---- two-level scan, pass 1: per-block sums ----
__global__ __launch_bounds__(256) void scan_bsum(const u32* __restrict__ counts,
                                                 u32* __restrict__ bsum) {
    __shared__ u32 ws[4];
    const int tid = threadIdx.x;
    int i = blockIdx.x * SCAN_ELEMS + tid * 4;
    u32 s = 0;
    if (i < NN) {               // NN % 4 == 0, so full uint4 is safe when i < NN
        uint4 c = *reinterpret_cast<const uint4*>(counts + i);
        s = c.x + c.y + c.z + c.w;
    }
    u32 r = s;
    #pragma unroll
    for (int off = 1; off < 64; off <<= 1) r += __shfl_xor(r, off, 64);
    if ((tid & 63) == 0) ws[tid >> 6] = r;
    __syncthreads();
    if (tid == 0) bsum[blockIdx.x] = ws[0] + ws[1] + ws[2] + ws[3];
}

// ---- pass 2: exclusive scan of the 49 block sums (single wave) ----
__global__ void scan_boff(const u32* __restrict__ bsum, u32* __restrict__ boff) {
    int lane = threadIdx.x;    // 64 threads
    u32 v = (lane < NBLK) ? bsum[lane] : 0u;
    u32 inc = v;
    #pragma unroll
    for (int off = 1; off < 64; off <<= 1) {
        u32 y = __shfl_up(inc, off, 64);
        if (lane >= off) inc += y;
    }
    if (lane < NBLK) boff[lane] = inc - v;
}

// ---- pass 3: intra-block exclusive scan + block offset -> rowptr, dinv ----
__global__ __launch_bounds__(256) void scan_final(const u32* __restrict__ counts,
                                                  const u32* __restrict__ boff,
                                                  u32* __restrict__ rowptr,
                                                  float* __restrict__ dinv) {
    __shared__ u32 ws[4];
    const int tid = threadIdx.x;
    const int lane = tid & 63, wv = tid >> 6;
    int i = blockIdx.x * SCAN_ELEMS + tid * 4;
    u32 c[4] = {0u, 0u, 0u, 0u};
    u32 s = 0;
    if (i < NN) {
        uint4 cc = *reinterpret_cast<const uint4*>(counts + i);
        c[0] = cc.x; c[1] = cc.y; c[2] = cc.z; c[3] = cc.w;
        s = cc.x + cc.y + cc.z + cc.w;
    }
    // wave-inclusive scan of per-thread sums
    u32 inc = s;
    #pragma unroll
    for (int off = 1; off < 64; off <<= 1) {
        u32 y = __shfl_up(inc, off, 64);
        if (lane >= off) inc += y;
    }
    if (lane == 63) ws[wv] = inc;
    __syncthreads();
    u32 woff = 0;
    #pragma unroll
    for (int j = 0; j < 4; ++j) if (j < wv) woff += ws[j];
    u32 run = boff[blockIdx.x] + woff + inc - s;   // exclusive offset for c[0]
    #pragma unroll
    for (int j = 0; j < 4; ++j) {
        int ii = i + j;
        if (ii < NN) {
            rowptr[ii] = run;
            run += c[j];
            dinv[ii] = rsqrtf((float)(c[j] + 1u));   // +1 self loop; always > 0
        }
    }
    if (blockIdx.x == 0 && tid == 0) rowptr[NN] = NE;
}

// ---- scatter edge sources into CSR ----
__global__ void scatter_kernel(const int* __restrict__ src, const int* __restrict__ dst,
                               const u32* __restrict__ rowptr, u32* __restrict__ cursor,
                               u32* __restrict__ srclist) {
    int e = blockIdx.x * blockDim.x + threadIdx.x;
    if (e < NE) {
        int d = dst[e];
        u32 r = atomicAdd(&cursor[d], 1u);
        srclist[rowptr[d] + r] = (u32)src[e];
    }
}

// ---- aggregation: one wave per node; 4 edge slots x 16 lanes x 8 features ----
__global__ __launch_bounds__(256) void agg_kernel(
        const u16* __restrict__ xh, const u32* __restrict__ rowptr,
        const u32* __restrict__ srclist, const float* __restrict__ dinv,
        u16* __restrict__ aggX) {
    int wid = (blockIdx.x * blockDim.x + threadIdx.x) >> 6;
    if (wid >= NN) return;
    const int lane = threadIdx.x & 63;
    const int eq = lane >> 4;      // edge slot 0..3
    const int fl = lane & 15;      // feature slice (8 bf16 = 16B)
    const int v = wid;
    const float dv = dinv[v];
    float acc[8];
    {
        uint4 sv = reinterpret_cast<const uint4*>(xh + (size_t)v * HD)[fl];
        float f[8]; unpack8(sv, f);
        float s = (eq == 0) ? dv : 0.f;       // self-loop term dv^2*x[v] (dv applied again at end)
        #pragma unroll
        for (int j = 0; j < 8; ++j) acc[j] = s * f[j];
    }
    const u32 rs = rowptr[v], re = rowptr[v + 1];
    for (u32 i = rs + eq; i < re; i += 4) {
        u32 u = srclist[i];
        float du = dinv[u];
        uint4 mu = reinterpret_cast<const uint4*>(xh + (size_t)u * HD)[fl];
        float f[8]; unpack8(mu, f);
        #pragma unroll
        for (int j = 0; j < 8; ++j) acc[j] = fmaf(du, f[j], acc[j]);
    }
    #pragma unroll
    for (int j = 0; j < 8; ++j) {
        acc[j] += __shfl_xor(acc[j], 16, 64);
        acc[j] += __shfl_xor(acc[j], 32, 64);
    }
    if (eq == 0) {
        u32 w[4];
        #pragma unroll
        for (int q = 0; q < 4; ++q) {
            w[q] = (u32)f2bf(dv * acc[2 * q]) | ((u32)f2bf(dv * acc[2 * q + 1]) << 16);
        }
        reinterpret_cast<uint4*>(aggX + (size_t)v * HD)[fl] =
            make_uint4(w[0], w[1], w[2], w[3]);
    }
}

// ---- GEMM: agg = aggX @ W + b (fp32 VALU, bf16 operands), fused BN stats ----
__global__ __launch_bounds__(256) void gemm_kernel(
        const u16* __restrict__ aggX, const u16* __restrict__ wt,
        const float* __restrict__ bias,
        u16* __restrict__ agg, float* __restrict__ colsum, float* __restrict__ colsq) {
    __shared__ u16 Ws[128 * 132];     // wt staged, stride 132 -> 2-way max bank aliasing
    __shared__ u16 xs[32 * 128];
    __shared__ float cs_l[128];
    __shared__ float cq_l[128];
    const int tid = threadIdx.x;
    const int rbase = blockIdx.x * 32;
    if (tid < 128) { cs_l[tid] = 0.f; cq_l[tid] = 0.f; }
    for (int q = tid; q < 128 * 32; q += 256) {          // 4096 uint2 of W
        int c = q >> 5, kq = q & 31;
        uint2 w = reinterpret_cast<const uint2*>(wt)[q];
        *reinterpret_cast<uint2*>(&Ws[c * 132 + kq * 4]) = w;
    }
    for (int q = tid; q < 32 * 32; q += 256) {           // 1024 uint2 of x tile
        int rr = q >> 5, kq = q & 31;
        int row = rbase + rr;
        uint2 w = (row < NN) ? reinterpret_cast<const uint2*>(aggX + (size_t)row * HD)[kq]
                             : make_uint2(0u, 0u);
        *reinterpret_cast<uint2*>(&xs[rr * 128 + kq * 4]) = w;
    }
    __syncthreads();
    const int rg = tid >> 5, cg = tid & 31;   // rows rg+8i, cols cg+32j
    float acc[4][4] = {};
    for (int k = 0; k < 128; k += 4) {
        float xf[4][4], wf[4][4];
        #pragma unroll
        for (int i = 0; i < 4; ++i) {
            uint2 a = *reinterpret_cast<const uint2*>(&xs[(rg + 8 * i) * 128 + k]);
            xf[i][0] = __uint_as_float(a.x << 16); xf[i][1] = __uint_as_float(a.x & 0xFFFF0000u);
            xf[i][2] = __uint_as_float(a.y << 16); xf[i][3] = __uint_as_float(a.y & 0xFFFF0000u);
        }
        #pragma unroll
        for (int j = 0; j < 4; ++j) {
            uint2 w = *reinterpret_cast<const uint2*>(&Ws[(cg + 32 * j) * 132 + k]);
            wf[j][0] = __uint_as_float(w.x << 16); wf[j][1] = __uint_as_float(w.x & 0xFFFF0000u);
            wf[j][2] = __uint_as_float(w.y << 16); wf[j][3] = __uint_as_float(w.y & 0xFFFF0000u);
        }
        #pragma unroll
        for (int i = 0; i < 4; ++i)
            #pragma unroll
            for (int j = 0; j < 4; ++j)
                #pragma unroll
                for (int kk = 0; kk < 4; ++kk)
                    acc[i][j] = fmaf(xf[i][kk], wf[j][kk], acc[i][j]);
    }
    float bj[4];
    #pragma unroll
    for (int j = 0; j < 4; ++j) bj[j] = bias[cg + 32 * j];
    float cp[4] = {0.f, 0.f, 0.f, 0.f}, cq[4] = {0.f, 0.f, 0.f, 0.f};
    #pragma unroll
    for (int i = 0; i < 4; ++i) {
        int row = rbase + rg + 8 * i;
        if (row < NN) {
            #pragma unroll
            for (int j = 0; j < 4; ++j) {
                float vv = acc[i][j] + bj[j];
                agg[(size_t)row * HD + cg + 32 * j] = f2bf(vv);
                cp[j] += vv;
                cq[j] += vv * vv;
            }
        }
    }
    #pragma unroll
    for (int j = 0; j < 4; ++j) {
        atomicAdd(&cs_l[cg + 32 * j], cp[j]);
        atomicAdd(&cq_l[cg + 32 * j], cq[j]);
    }
    __syncthreads();
    if (tid < 128) {
        atomicAdd(&colsum[tid], cs_l[tid]);
        atomicAdd(&colsq[tid], cq_l[tid]);
    }
}

// ---- BN stats finalize ----
__global__ void stats_kernel(const float* __restrict__ colsum, const float* __restrict__ colsq,
                             const float* __restrict__ gamma, const float* __restrict__ beta,
                             float* __restrict__ sc, float* __restrict__ sh) {
    int c = threadIdx.x;
    float m = colsum[c] * (1.f / NN);
    float var = colsq[c] * (1.f / NN) - m * m;
    float inv = rsqrtf(var + 1e-5f);
    float s = gamma[c] * inv;
    sc[c] = s;
    sh[c] = beta[c] - m * s;
}

// ---- normalize + ReLU + residual ----
__global__ void final_kernel(const u16* __restrict__ agg, const float* __restrict__ last_x,
                             const float* __restrict__ sc, const float* __restrict__ sh,
                             float* __restrict__ out) {
    int idx = blockIdx.x * blockDim.x + threadIdx.x;   // NN*HD/4 threads
    int c0 = (idx * 4) & 127;
    uint2 a = reinterpret_cast<const uint2*>(agg)[idx];
    float4 lx = reinterpret_cast<const float4*>(last_x)[idx];
    float f0 = __uint_as_float(a.x << 16), f1 = __uint_as_float(a.x & 0xFFFF0000u);
    float f2 = __uint_as_float(a.y << 16), f3 = __uint_as_float(a.y & 0xFFFF0000u);
    float4 o;
    o.x = fmaxf(fmaf(f0, sc[c0 + 0], sh[c0 + 0]), 0.f) + lx.x;
    o.y = fmaxf(fmaf(f1, sc[c0 + 1], sh[c0 + 1]), 0.f) + lx.y;
    o.z = fmaxf(fmaf(f2, sc[c0 + 2], sh[c0 + 2]), 0.f) + lx.z;
    o.w = fmaxf(fmaf(f3, sc[c0 + 3], sh[c0 + 3]), 0.f) + lx.w;
    reinterpret_cast<float4*>(out)[idx] = o;
}

extern "C" void kernel_launch(void* const* d_in, const int* in_sizes, int n_in,
                              void* d_out, int out_size, void* d_ws, size_t ws_size,
                              hipStream_t stream) {
    const float* x      = (const float*)d_in[0];
    const float* last_x = (const float*)d_in[1];
    const int*   edge   = (const int*)d_in[2];   // [2][NE]
    const float* W      = (const float*)d_in[3];
    const float* bias   = (const float*)d_in[4];
    const float* gamma  = (const float*)d_in[5];
    const float* beta   = (const float*)d_in[6];
    float* out = (float*)d_out;

    char* ws = (char*)d_ws;
    size_t p = 0;
    auto take = [&](size_t bytes) { size_t r = p; p += (bytes + 255) & ~255ULL; return r; };
    u32*   counts  = (u32*)(ws + take((size_t)NN * 4));
    u32*   rowptr  = (u32*)(ws + take((size_t)(NN + 1) * 4));
    u32*   cursor  = (u32*)(ws + take((size_t)NN * 4));
    u32*   srclist = (u32*)(ws + take((size_t)NE * 4));
    float* dinv    = (float*)(ws + take((size_t)NN * 4));
    u16*   xh      = (u16*)(ws + take((size_t)NN * HD * 2));
    u16*   aggX    = (u16*)(ws + take((size_t)NN * HD * 2));
    u16*   aggb    = (u16*)(ws + take((size_t)NN * HD * 2));
    u16*   wt      = (u16*)(ws + take((size_t)HD * HD * 2));
    float* colsum  = (float*)(ws + take((size_t)HD * 4));
    float* colsq   = (float*)(ws + take((size_t)HD * 4));
    float* sc      = (float*)(ws + take((size_t)HD * 4));
    float* sh      = (float*)(ws + take((size_t)HD * 4));
    u32*   bsum    = (u32*)(ws + take((size_t)NBLK * 4));
    u32*   boff    = (u32*)(ws + take((size_t)NBLK * 4));

    const int* srcp = edge;
    const int* dstp = edge + NE;

    prep_kernel<<<(NN * HD / 4) / 256, 256, 0, stream>>>(x, W, xh, wt, counts, cursor, colsum, colsq);
    hist_kernel<<<(NE + 255) / 256, 256, 0, stream>>>(dstp, counts);
    scan_bsum<<<NBLK, 256, 0, stream>>>(counts, bsum);
    scan_boff<<<1, 64, 0, stream>>>(bsum, boff);
    scan_final<<<NBLK, 256, 0, stream>>>(counts, boff, rowptr, dinv);
    scatter_kernel<<<(NE + 255) / 256, 256, 0, stream>>>(srcp, dstp, rowptr, cursor, srclist);
    agg_kernel<<<(NN + 3) / 4, 256, 0, stream>>>(xh, rowptr, srclist, dinv, aggX);
    gemm_kernel<<<(NN + 31) / 32, 256, 0, stream>>>(aggX, wt, bias, aggb, colsum, colsq);
    stats_kernel<<<1, HD, 0, stream>>>(colsum, colsq, gamma, beta, sc, sh);
    final_kernel<<<(NN * HD / 4) / 256, 256, 0, stream>>>(aggb, last_x, sc, sh, out);
}

// Round 3
// 179.256 us; speedup vs baseline: 1.8030x; 1.1408x over previous
//
#include <hip/hip_runtime.h>
#include <hip/hip_bf16.h>
#include <math.h>

#define NN 50000
#define NE 800000
#define HD 128
#define SCAN_ELEMS 1024                       // elements per scan block
#define NBLK ((NN + SCAN_ELEMS - 1) / SCAN_ELEMS)   // 49

typedef unsigned int u32;
typedef unsigned short u16;
typedef __attribute__((ext_vector_type(8))) __bf16 bf16x8;
typedef __attribute__((ext_vector_type(4))) float f32x4;

__device__ __forceinline__ u16 f2bf(float f) {
    u32 u = __float_as_uint(f);
    u32 r = u + 0x7FFFu + ((u >> 16) & 1u);   // round-to-nearest-even
    return (u16)(r >> 16);
}
__device__ __forceinline__ void unpack8(uint4 p, float* f) {
    f[0] = __uint_as_float(p.x << 16); f[1] = __uint_as_float(p.x & 0xFFFF0000u);
    f[2] = __uint_as_float(p.y << 16); f[3] = __uint_as_float(p.y & 0xFFFF0000u);
    f[4] = __uint_as_float(p.z << 16); f[5] = __uint_as_float(p.z & 0xFFFF0000u);
    f[6] = __uint_as_float(p.w << 16); f[7] = __uint_as_float(p.w & 0xFFFF0000u);
}

// ---- prep: zero counters, convert x -> bf16, W -> MFMA-fragment layout ----
// Wf tile t = c0*4+k0 (c0: 16-col tile, k0: 32-k tile); within tile, lane ln
// holds 8 consecutive-k bf16: Wf[(t*64+ln)*8 + j] = W[k0*32+(ln>>4)*8+j][c0*16+(ln&15)]
__global__ void prep_kernel(const float* __restrict__ x, const float* __restrict__ W,
                            u16* __restrict__ xh, u16* __restrict__ wf,
                            u32* __restrict__ counts, u32* __restrict__ cursor,
                            float* __restrict__ colsum, float* __restrict__ colsq) {
    int idx = blockIdx.x * blockDim.x + threadIdx.x;   // exactly NN*HD/4 threads
    {
        const float4 v = reinterpret_cast<const float4*>(x)[idx];
        u32 lo = (u32)f2bf(v.x) | ((u32)f2bf(v.y) << 16);
        u32 hi = (u32)f2bf(v.z) | ((u32)f2bf(v.w) << 16);
        reinterpret_cast<uint2*>(xh)[idx] = make_uint2(lo, hi);
    }
    if (idx < NN) { counts[idx] = 0u; cursor[idx] = 0u; }
    if (idx < HD * HD) {
        int t  = idx >> 9;           // 0..31
        int c0 = t >> 2, k0 = t & 3;
        int ln = (idx >> 3) & 63;
        int j  = idx & 7;
        int k  = k0 * 32 + (ln >> 4) * 8 + j;
        int c  = c0 * 16 + (ln & 15);
        wf[idx] = f2bf(W[k * HD + c]);
    }
    if (idx < HD) { colsum[idx] = 0.f; colsq[idx] = 0.f; }
}

// ---- histogram of in-degrees ----
__global__ void hist_kernel(const int* __restrict__ dst, u32* __restrict__ counts) {
    int e = blockIdx.x * blockDim.x + threadIdx.x;
    if (e < NE) atomicAdd(&counts[dst[e]], 1u);
}

// ---- two-level scan, pass 1: per-block sums ----
__global__ __launch_bounds__(256) void scan_bsum(const u32* __restrict__ counts,
                                                 u32* __restrict__ bsum) {
    __shared__ u32 ws[4];
    const int tid = threadIdx.x;
    int i = blockIdx.x * SCAN_ELEMS + tid * 4;
    u32 s = 0;
    if (i < NN) {               // NN % 4 == 0, so full uint4 is safe when i < NN
        uint4 c = *reinterpret_cast<const uint4*>(counts + i);
        s = c.x + c.y + c.z + c.w;
    }
    u32 r = s;
    #pragma unroll
    for (int off = 1; off < 64; off <<= 1) r += __shfl_xor(r, off, 64);
    if ((tid & 63) == 0) ws[tid >> 6] = r;
    __syncthreads();
    if (tid == 0) bsum[blockIdx.x] = ws[0] + ws[1] + ws[2] + ws[3];
}

// ---- pass 2: exclusive scan of the 49 block sums (single wave) ----
__global__ void scan_boff(const u32* __restrict__ bsum, u32* __restrict__ boff) {
    int lane = threadIdx.x;    // 64 threads
    u32 v = (lane < NBLK) ? bsum[lane] : 0u;
    u32 inc = v;
    #pragma unroll
    for (int off = 1; off < 64; off <<= 1) {
        u32 y = __shfl_up(inc, off, 64);
        if (lane >= off) inc += y;
    }
    if (lane < NBLK) boff[lane] = inc - v;
}

// ---- pass 3: intra-block exclusive scan + block offset -> rowptr, dinv ----
__global__ __launch_bounds__(256) void scan_final(const u32* __restrict__ counts,
                                                  const u32* __restrict__ boff,
                                                  u32* __restrict__ rowptr,
                                                  float* __restrict__ dinv) {
    __shared__ u32 ws[4];
    const int tid = threadIdx.x;
    const int lane = tid & 63, wv = tid >> 6;
    int i = blockIdx.x * SCAN_ELEMS + tid * 4;
    u32 c[4] = {0u, 0u, 0u, 0u};
    u32 s = 0;
    if (i < NN) {
        uint4 cc = *reinterpret_cast<const uint4*>(counts + i);
        c[0] = cc.x; c[1] = cc.y; c[2] = cc.z; c[3] = cc.w;
        s = cc.x + cc.y + cc.z + cc.w;
    }
    u32 inc = s;
    #pragma unroll
    for (int off = 1; off < 64; off <<= 1) {
        u32 y = __shfl_up(inc, off, 64);
        if (lane >= off) inc += y;
    }
    if (lane == 63) ws[wv] = inc;
    __syncthreads();
    u32 woff = 0;
    #pragma unroll
    for (int j = 0; j < 4; ++j) if (j < wv) woff += ws[j];
    u32 run = boff[blockIdx.x] + woff + inc - s;   // exclusive offset for c[0]
    #pragma unroll
    for (int j = 0; j < 4; ++j) {
        int ii = i + j;
        if (ii < NN) {
            rowptr[ii] = run;
            run += c[j];
            dinv[ii] = rsqrtf((float)(c[j] + 1u));   // +1 self loop; always > 0
        }
    }
    if (blockIdx.x == 0 && tid == 0) rowptr[NN] = NE;
}

// ---- scatter edge sources into CSR ----
__global__ void scatter_kernel(const int* __restrict__ src, const int* __restrict__ dst,
                               const u32* __restrict__ rowptr, u32* __restrict__ cursor,
                               u32* __restrict__ srclist) {
    int e = blockIdx.x * blockDim.x + threadIdx.x;
    if (e < NE) {
        int d = dst[e];
        u32 r = atomicAdd(&cursor[d], 1u);
        srclist[rowptr[d] + r] = (u32)src[e];
    }
}

// ---- aggregation: one wave per node; 4 edge slots x 16 lanes x 8 features ----
__global__ __launch_bounds__(256) void agg_kernel(
        const u16* __restrict__ xh, const u32* __restrict__ rowptr,
        const u32* __restrict__ srclist, const float* __restrict__ dinv,
        u16* __restrict__ aggX) {
    int wid = (blockIdx.x * blockDim.x + threadIdx.x) >> 6;
    if (wid >= NN) return;
    const int lane = threadIdx.x & 63;
    const int eq = lane >> 4;      // edge slot 0..3
    const int fl = lane & 15;      // feature slice (8 bf16 = 16B)
    const int v = wid;
    const float dv = dinv[v];
    float acc[8];
    {
        uint4 sv = reinterpret_cast<const uint4*>(xh + (size_t)v * HD)[fl];
        float f[8]; unpack8(sv, f);
        float s = (eq == 0) ? dv : 0.f;       // self-loop term dv^2*x[v] (dv applied again at end)
        #pragma unroll
        for (int j = 0; j < 8; ++j) acc[j] = s * f[j];
    }
    const u32 rs = rowptr[v], re = rowptr[v + 1];
    for (u32 i = rs + eq; i < re; i += 4) {
        u32 u = srclist[i];
        float du = dinv[u];
        uint4 mu = reinterpret_cast<const uint4*>(xh + (size_t)u * HD)[fl];
        float f[8]; unpack8(mu, f);
        #pragma unroll
        for (int j = 0; j < 8; ++j) acc[j] = fmaf(du, f[j], acc[j]);
    }
    #pragma unroll
    for (int j = 0; j < 8; ++j) {
        acc[j] += __shfl_xor(acc[j], 16, 64);
        acc[j] += __shfl_xor(acc[j], 32, 64);
    }
    if (eq == 0) {
        u32 w[4];
        #pragma unroll
        for (int q = 0; q < 4; ++q) {
            w[q] = (u32)f2bf(dv * acc[2 * q]) | ((u32)f2bf(dv * acc[2 * q + 1]) << 16);
        }
        reinterpret_cast<uint4*>(aggX + (size_t)v * HD)[fl] =
            make_uint4(w[0], w[1], w[2], w[3]);
    }
}

// ---- MFMA GEMM: agg = aggX @ W + b, fused BN stats ----
// wave = 16 rows; block = 4 waves = 64 rows. A from global, B (Wf) via LDS.
__global__ __launch_bounds__(256) void gemm_kernel(
        const u16* __restrict__ aggX, const u16* __restrict__ wf,
        const float* __restrict__ bias,
        u16* __restrict__ agg, float* __restrict__ colsum, float* __restrict__ colsq) {
    __shared__ u16 Bs[32 * 512];      // 32 KB: 32 tiles x 64 lanes x 8 bf16
    __shared__ float cs_l[128];
    __shared__ float cq_l[128];
    const int tid = threadIdx.x;
    if (tid < 128) { cs_l[tid] = 0.f; cq_l[tid] = 0.f; }
    for (int q = tid; q < 2048; q += 256)
        reinterpret_cast<uint4*>(Bs)[q] = reinterpret_cast<const uint4*>(wf)[q];
    __syncthreads();

    const int lane = tid & 63, wave = tid >> 6;
    const int r0 = blockIdx.x * 64 + wave * 16;
    const int rrow = r0 + (lane & 15);          // A-fragment row for this lane
    const int rgrp = lane >> 4;

    bf16x8 a[4];
    #pragma unroll
    for (int k0 = 0; k0 < 4; ++k0) {
        if (rrow < NN) {
            a[k0] = *reinterpret_cast<const bf16x8*>(
                aggX + (size_t)rrow * HD + k0 * 32 + rgrp * 8);
        } else {
            a[k0] = bf16x8{};
        }
    }

    f32x4 acc[8];
    #pragma unroll
    for (int c0 = 0; c0 < 8; ++c0) acc[c0] = f32x4{0.f, 0.f, 0.f, 0.f};

    #pragma unroll
    for (int c0 = 0; c0 < 8; ++c0) {
        #pragma unroll
        for (int k0 = 0; k0 < 4; ++k0) {
            bf16x8 b = *reinterpret_cast<const bf16x8*>(
                Bs + ((c0 * 4 + k0) * 64 + lane) * 8);
            acc[c0] = __builtin_amdgcn_mfma_f32_16x16x32_bf16(a[k0], b, acc[c0], 0, 0, 0);
        }
    }

    // epilogue: bias, bf16 store, BN partial stats
    // C/D layout: col = lane&15 (within tile), row = rgrp*4 + reg
    #pragma unroll
    for (int c0 = 0; c0 < 8; ++c0) {
        int col = c0 * 16 + (lane & 15);
        float bcol = bias[col];
        float cp = 0.f, cq = 0.f;
        #pragma unroll
        for (int reg = 0; reg < 4; ++reg) {
            int row = r0 + rgrp * 4 + reg;
            if (row < NN) {
                float v = acc[c0][reg] + bcol;
                agg[(size_t)row * HD + col] = f2bf(v);
                cp += v;
                cq += v * v;
            }
        }
        atomicAdd(&cs_l[col], cp);
        atomicAdd(&cq_l[col], cq);
    }
    __syncthreads();
    if (tid < 128) {
        atomicAdd(&colsum[tid], cs_l[tid]);
        atomicAdd(&colsq[tid], cq_l[tid]);
    }
}

// ---- BN stats finalize ----
__global__ void stats_kernel(const float* __restrict__ colsum, const float* __restrict__ colsq,
                             const float* __restrict__ gamma, const float* __restrict__ beta,
                             float* __restrict__ sc, float* __restrict__ sh) {
    int c = threadIdx.x;
    float m = colsum[c] * (1.f / NN);
    float var = colsq[c] * (1.f / NN) - m * m;
    float inv = rsqrtf(var + 1e-5f);
    float s = gamma[c] * inv;
    sc[c] = s;
    sh[c] = beta[c] - m * s;
}

// ---- normalize + ReLU + residual ----
__global__ void final_kernel(const u16* __restrict__ agg, const float* __restrict__ last_x,
                             const float* __restrict__ sc, const float* __restrict__ sh,
                             float* __restrict__ out) {
    int idx = blockIdx.x * blockDim.x + threadIdx.x;   // NN*HD/4 threads
    int c0 = (idx * 4) & 127;
    uint2 a = reinterpret_cast<const uint2*>(agg)[idx];
    float4 lx = reinterpret_cast<const float4*>(last_x)[idx];
    float f0 = __uint_as_float(a.x << 16), f1 = __uint_as_float(a.x & 0xFFFF0000u);
    float f2 = __uint_as_float(a.y << 16), f3 = __uint_as_float(a.y & 0xFFFF0000u);
    float4 o;
    o.x = fmaxf(fmaf(f0, sc[c0 + 0], sh[c0 + 0]), 0.f) + lx.x;
    o.y = fmaxf(fmaf(f1, sc[c0 + 1], sh[c0 + 1]), 0.f) + lx.y;
    o.z = fmaxf(fmaf(f2, sc[c0 + 2], sh[c0 + 2]), 0.f) + lx.z;
    o.w = fmaxf(fmaf(f3, sc[c0 + 3], sh[c0 + 3]), 0.f) + lx.w;
    reinterpret_cast<float4*>(out)[idx] = o;
}

extern "C" void kernel_launch(void* const* d_in, const int* in_sizes, int n_in,
                              void* d_out, int out_size, void* d_ws, size_t ws_size,
                              hipStream_t stream) {
    const float* x      = (const float*)d_in[0];
    const float* last_x = (const float*)d_in[1];
    const int*   edge   = (const int*)d_in[2];   // [2][NE]
    const float* W      = (const float*)d_in[3];
    const float* bias   = (const float*)d_in[4];
    const float* gamma  = (const float*)d_in[5];
    const float* beta   = (const float*)d_in[6];
    float* out = (float*)d_out;

    char* ws = (char*)d_ws;
    size_t p = 0;
    auto take = [&](size_t bytes) { size_t r = p; p += (bytes + 255) & ~255ULL; return r; };
    u32*   counts  = (u32*)(ws + take((size_t)NN * 4));
    u32*   rowptr  = (u32*)(ws + take((size_t)(NN + 1) * 4));
    u32*   cursor  = (u32*)(ws + take((size_t)NN * 4));
    u32*   srclist = (u32*)(ws + take((size_t)NE * 4));
    float* dinv    = (float*)(ws + take((size_t)NN * 4));
    u16*   xh      = (u16*)(ws + take((size_t)NN * HD * 2));
    u16*   aggX    = (u16*)(ws + take((size_t)NN * HD * 2));
    u16*   aggb    = (u16*)(ws + take((size_t)NN * HD * 2));
    u16*   wf      = (u16*)(ws + take((size_t)HD * HD * 2));
    float* colsum  = (float*)(ws + take((size_t)HD * 4));
    float* colsq   = (float*)(ws + take((size_t)HD * 4));
    float* sc      = (float*)(ws + take((size_t)HD * 4));
    float* sh      = (float*)(ws + take((size_t)HD * 4));
    u32*   bsum    = (u32*)(ws + take((size_t)NBLK * 4));
    u32*   boff    = (u32*)(ws + take((size_t)NBLK * 4));

    const int* srcp = edge;
    const int* dstp = edge + NE;

    prep_kernel<<<(NN * HD / 4) / 256, 256, 0, stream>>>(x, W, xh, wf, counts, cursor, colsum, colsq);
    hist_kernel<<<(NE + 255) / 256, 256, 0, stream>>>(dstp, counts);
    scan_bsum<<<NBLK, 256, 0, stream>>>(counts, bsum);
    scan_boff<<<1, 64, 0, stream>>>(bsum, boff);
    scan_final<<<NBLK, 256, 0, stream>>>(counts, boff, rowptr, dinv);
    scatter_kernel<<<(NE + 255) / 256, 256, 0, stream>>>(srcp, dstp, rowptr, cursor, srclist);
    agg_kernel<<<(NN + 3) / 4, 256, 0, stream>>>(xh, rowptr, srclist, dinv, aggX);
    gemm_kernel<<<(NN + 63) / 64, 256, 0, stream>>>(aggX, wf, bias, aggb, colsum, colsq);
    stats_kernel<<<1, HD, 0, stream>>>(colsum, colsq, gamma, beta, sc, sh);
    final_kernel<<<(NN * HD / 4) / 256, 256, 0, stream>>>(aggb, last_x, sc, sh, out);
}

// Round 4
// 162.668 us; speedup vs baseline: 1.9869x; 1.1020x over previous
//
#include <hip/hip_runtime.h>
#include <hip/hip_bf16.h>
#include <math.h>

#define NN 50000
#define NE 800000
#define HD 128
#define SCAN_ELEMS 1024
#define NBLK ((NN + SCAN_ELEMS - 1) / SCAN_ELEMS)   // 49
#define NBG ((NN + 63) / 64)                        // 782 gemm blocks
#define SCAT_BPC 104                                // scatter blocks per class
#define CLS_RANGE ((NN + 7) / 8)                    // 6250 dst-range per XCD class

typedef unsigned int u32;
typedef unsigned short u16;
typedef __attribute__((ext_vector_type(8))) __bf16 bf16x8;
typedef __attribute__((ext_vector_type(4))) float f32x4;

__device__ __forceinline__ u16 f2bf(float f) {
    u32 u = __float_as_uint(f);
    u32 r = u + 0x7FFFu + ((u >> 16) & 1u);   // round-to-nearest-even
    return (u16)(r >> 16);
}
__device__ __forceinline__ void unpack8(uint4 p, float* f) {
    f[0] = __uint_as_float(p.x << 16); f[1] = __uint_as_float(p.x & 0xFFFF0000u);
    f[2] = __uint_as_float(p.y << 16); f[3] = __uint_as_float(p.y & 0xFFFF0000u);
    f[4] = __uint_as_float(p.z << 16); f[5] = __uint_as_float(p.z & 0xFFFF0000u);
    f[6] = __uint_as_float(p.w << 16); f[7] = __uint_as_float(p.w & 0xFFFF0000u);
}

// ---- prep: zero counters, x -> bf16, W -> MFMA fragment layout ----
// Tile t = c0*4+k0, c0=0..7, k0=0..3. Lane ln, elem j holds
// W[k0*32+(ln>>4)*8+j][(ln&15)*8 + c0]  -> output col of (tile c0, pos p) is p*8+c0,
// so each lane's 8 c0-outputs are 8 CONSECUTIVE columns (coalesced C stores).
__global__ void prep_kernel(const float* __restrict__ x, const float* __restrict__ W,
                            u16* __restrict__ xh, u16* __restrict__ wf,
                            u32* __restrict__ counts, u32* __restrict__ cursor) {
    int idx = blockIdx.x * blockDim.x + threadIdx.x;   // exactly NN*HD/4 threads
    {
        const float4 v = reinterpret_cast<const float4*>(x)[idx];
        u32 lo = (u32)f2bf(v.x) | ((u32)f2bf(v.y) << 16);
        u32 hi = (u32)f2bf(v.z) | ((u32)f2bf(v.w) << 16);
        reinterpret_cast<uint2*>(xh)[idx] = make_uint2(lo, hi);
    }
    if (idx < NN) { counts[idx] = 0u; cursor[idx] = 0u; }
    if (idx < HD * HD) {
        int t  = idx >> 9;           // 0..31
        int c0 = t >> 2, k0 = t & 3;
        int ln = (idx >> 3) & 63;
        int j  = idx & 7;
        int k  = k0 * 32 + (ln >> 4) * 8 + j;
        int c  = (ln & 15) * 8 + c0;
        wf[idx] = f2bf(W[k * HD + c]);
    }
}

// ---- histogram of in-degrees ----
__global__ void hist_kernel(const int* __restrict__ dst, u32* __restrict__ counts) {
    int e = blockIdx.x * blockDim.x + threadIdx.x;
    if (e < NE) atomicAdd(&counts[dst[e]], 1u);
}

// ---- two-level scan, pass 1: per-block sums ----
__global__ __launch_bounds__(256) void scan_bsum(const u32* __restrict__ counts,
                                                 u32* __restrict__ bsum) {
    __shared__ u32 ws[4];
    const int tid = threadIdx.x;
    int i = blockIdx.x * SCAN_ELEMS + tid * 4;
    u32 s = 0;
    if (i < NN) {
        uint4 c = *reinterpret_cast<const uint4*>(counts + i);
        s = c.x + c.y + c.z + c.w;
    }
    u32 r = s;
    #pragma unroll
    for (int off = 1; off < 64; off <<= 1) r += __shfl_xor(r, off, 64);
    if ((tid & 63) == 0) ws[tid >> 6] = r;
    __syncthreads();
    if (tid == 0) bsum[blockIdx.x] = ws[0] + ws[1] + ws[2] + ws[3];
}

// ---- pass 2: exclusive scan of the 49 block sums (single wave) ----
__global__ void scan_boff(const u32* __restrict__ bsum, u32* __restrict__ boff) {
    int lane = threadIdx.x;
    u32 v = (lane < NBLK) ? bsum[lane] : 0u;
    u32 inc = v;
    #pragma unroll
    for (int off = 1; off < 64; off <<= 1) {
        u32 y = __shfl_up(inc, off, 64);
        if (lane >= off) inc += y;
    }
    if (lane < NBLK) boff[lane] = inc - v;
}

// ---- pass 3: intra-block exclusive scan -> rowptr, dinv ----
__global__ __launch_bounds__(256) void scan_final(const u32* __restrict__ counts,
                                                  const u32* __restrict__ boff,
                                                  u32* __restrict__ rowptr,
                                                  float* __restrict__ dinv) {
    __shared__ u32 ws[4];
    const int tid = threadIdx.x;
    const int lane = tid & 63, wv = tid >> 6;
    int i = blockIdx.x * SCAN_ELEMS + tid * 4;
    u32 c[4] = {0u, 0u, 0u, 0u};
    u32 s = 0;
    if (i < NN) {
        uint4 cc = *reinterpret_cast<const uint4*>(counts + i);
        c[0] = cc.x; c[1] = cc.y; c[2] = cc.z; c[3] = cc.w;
        s = cc.x + cc.y + cc.z + cc.w;
    }
    u32 inc = s;
    #pragma unroll
    for (int off = 1; off < 64; off <<= 1) {
        u32 y = __shfl_up(inc, off, 64);
        if (lane >= off) inc += y;
    }
    if (lane == 63) ws[wv] = inc;
    __syncthreads();
    u32 woff = 0;
    #pragma unroll
    for (int j = 0; j < 4; ++j) if (j < wv) woff += ws[j];
    u32 run = boff[blockIdx.x] + woff + inc - s;
    #pragma unroll
    for (int j = 0; j < 4; ++j) {
        int ii = i + j;
        if (ii < NN) {
            rowptr[ii] = run;
            run += c[j];
            dinv[ii] = rsqrtf((float)(c[j] + 1u));
        }
    }
    if (blockIdx.x == 0 && tid == 0) rowptr[NN] = NE;
}

// ---- scatter, XCD-partitioned: class = blockIdx&7 owns a dst range, so
// same-line srclist writes stay in one XCD's L2 and combine ----
__global__ __launch_bounds__(256) void scatter_kernel(
        const int* __restrict__ src, const int* __restrict__ dst,
        const u32* __restrict__ rowptr, u32* __restrict__ cursor,
        u32* __restrict__ srclist) {
    const int cls = blockIdx.x & 7;
    const int blk = blockIdx.x >> 3;
    const int lo = cls * CLS_RANGE;
    const int hi = (lo + CLS_RANGE < NN) ? lo + CLS_RANGE : NN;
    for (int e = blk * 256 + threadIdx.x; e < NE; e += SCAT_BPC * 256) {
        int d = dst[e];
        if (d >= lo && d < hi) {
            u32 r = atomicAdd(&cursor[d], 1u);
            srclist[rowptr[d] + r] = (u32)src[e];
        }
    }
}

// ---- aggregation: one wave per node; 4 edge slots x 16 lanes x 8 features ----
__global__ __launch_bounds__(256) void agg_kernel(
        const u16* __restrict__ xh, const u32* __restrict__ rowptr,
        const u32* __restrict__ srclist, const float* __restrict__ dinv,
        u16* __restrict__ aggX) {
    int wid = (blockIdx.x * blockDim.x + threadIdx.x) >> 6;
    if (wid >= NN) return;
    const int lane = threadIdx.x & 63;
    const int eq = lane >> 4;
    const int fl = lane & 15;
    const int v = wid;
    const float dv = dinv[v];
    float acc[8];
    {
        uint4 sv = reinterpret_cast<const uint4*>(xh + (size_t)v * HD)[fl];
        float f[8]; unpack8(sv, f);
        float s = (eq == 0) ? dv : 0.f;
        #pragma unroll
        for (int j = 0; j < 8; ++j) acc[j] = s * f[j];
    }
    const u32 rs = rowptr[v], re = rowptr[v + 1];
    for (u32 i = rs + eq; i < re; i += 4) {
        u32 u = srclist[i];
        float du = dinv[u];
        uint4 mu = reinterpret_cast<const uint4*>(xh + (size_t)u * HD)[fl];
        float f[8]; unpack8(mu, f);
        #pragma unroll
        for (int j = 0; j < 8; ++j) acc[j] = fmaf(du, f[j], acc[j]);
    }
    #pragma unroll
    for (int j = 0; j < 8; ++j) {
        acc[j] += __shfl_xor(acc[j], 16, 64);
        acc[j] += __shfl_xor(acc[j], 32, 64);
    }
    if (eq == 0) {
        u32 w[4];
        #pragma unroll
        for (int q = 0; q < 4; ++q) {
            w[q] = (u32)f2bf(dv * acc[2 * q]) | ((u32)f2bf(dv * acc[2 * q + 1]) << 16);
        }
        reinterpret_cast<uint4*>(aggX + (size_t)v * HD)[fl] =
            make_uint4(w[0], w[1], w[2], w[3]);
    }
}

// ---- MFMA GEMM: agg = aggX @ W + b; coalesced uint4 C-stores; BN stats via
// butterfly + per-block partials (NO global atomics) ----
__global__ __launch_bounds__(256) void gemm_kernel(
        const u16* __restrict__ aggX, const u16* __restrict__ wf,
        const float* __restrict__ bias,
        u16* __restrict__ agg, float* __restrict__ colpart) {
    __shared__ float cs_l[128];
    __shared__ float cq_l[128];
    const int tid = threadIdx.x;
    if (tid < 128) { cs_l[tid] = 0.f; cq_l[tid] = 0.f; }
    __syncthreads();

    const int lane = tid & 63, wave = tid >> 6;
    const int r0 = blockIdx.x * 64 + wave * 16;
    const int l15 = lane & 15, rgrp = lane >> 4;
    const int rrow = r0 + l15;

    bf16x8 a[4];
    #pragma unroll
    for (int k0 = 0; k0 < 4; ++k0) {
        if (rrow < NN)
            a[k0] = *reinterpret_cast<const bf16x8*>(aggX + (size_t)rrow * HD + k0 * 32 + rgrp * 8);
        else
            a[k0] = bf16x8{};
    }

    f32x4 acc[8];
    #pragma unroll
    for (int c0 = 0; c0 < 8; ++c0) acc[c0] = f32x4{0.f, 0.f, 0.f, 0.f};
    #pragma unroll
    for (int c0 = 0; c0 < 8; ++c0) {
        #pragma unroll
        for (int k0 = 0; k0 < 4; ++k0) {
            bf16x8 b = *reinterpret_cast<const bf16x8*>(wf + ((c0 * 4 + k0) * 64 + lane) * 8);
            acc[c0] = __builtin_amdgcn_mfma_f32_16x16x32_bf16(a[k0], b, acc[c0], 0, 0, 0);
        }
    }

    // lane's 8 output cols are consecutive: col = l15*8 + c0
    float4 b4a = *reinterpret_cast<const float4*>(bias + l15 * 8);
    float4 b4b = *reinterpret_cast<const float4*>(bias + l15 * 8 + 4);
    const float bcol[8] = {b4a.x, b4a.y, b4a.z, b4a.w, b4b.x, b4b.y, b4b.z, b4b.w};

    float cp[8] = {}, cq[8] = {};
    #pragma unroll
    for (int reg = 0; reg < 4; ++reg) {
        int row = r0 + rgrp * 4 + reg;
        float v[8];
        #pragma unroll
        for (int c0 = 0; c0 < 8; ++c0) v[c0] = acc[c0][reg] + bcol[c0];
        if (row < NN) {
            u32 w4[4];
            #pragma unroll
            for (int q = 0; q < 4; ++q)
                w4[q] = (u32)f2bf(v[2 * q]) | ((u32)f2bf(v[2 * q + 1]) << 16);
            *reinterpret_cast<uint4*>(agg + (size_t)row * HD + l15 * 8) =
                make_uint4(w4[0], w4[1], w4[2], w4[3]);
            #pragma unroll
            for (int c0 = 0; c0 < 8; ++c0) { cp[c0] += v[c0]; cq[c0] += v[c0] * v[c0]; }
        }
    }
    // butterfly over rgrp (lanes l15, l15+16, l15+32, l15+48)
    #pragma unroll
    for (int c0 = 0; c0 < 8; ++c0) {
        cp[c0] += __shfl_xor(cp[c0], 16, 64); cp[c0] += __shfl_xor(cp[c0], 32, 64);
        cq[c0] += __shfl_xor(cq[c0], 16, 64); cq[c0] += __shfl_xor(cq[c0], 32, 64);
    }
    if (rgrp == 0) {       // 4 waves -> 4-way LDS atomic contention only
        #pragma unroll
        for (int c0 = 0; c0 < 8; ++c0) {
            atomicAdd(&cs_l[l15 * 8 + c0], cp[c0]);
            atomicAdd(&cq_l[l15 * 8 + c0], cq[c0]);
        }
    }
    __syncthreads();
    if (tid < 128) {
        colpart[(size_t)blockIdx.x * 256 + tid] = cs_l[tid];
        colpart[(size_t)blockIdx.x * 256 + 128 + tid] = cq_l[tid];
    }
}

// ---- stats reduce stage A: 782 partial rows -> 64 ----
__global__ __launch_bounds__(256) void reduceA_kernel(const float* __restrict__ colpart,
                                                      float* __restrict__ colpart2) {
    int slot = threadIdx.x;
    float s = 0.f;
    for (int b = blockIdx.x; b < NBG; b += 64) s += colpart[(size_t)b * 256 + slot];
    colpart2[(size_t)blockIdx.x * 256 + slot] = s;
}

// ---- stats finalize: 64 rows -> mean/var -> scale/shift ----
__global__ __launch_bounds__(256) void stats_kernel(const float* __restrict__ colpart2,
                                                    const float* __restrict__ gamma,
                                                    const float* __restrict__ beta,
                                                    float* __restrict__ sc, float* __restrict__ sh) {
    __shared__ float sums[256];
    int slot = threadIdx.x;
    float s = 0.f;
    for (int b = 0; b < 64; ++b) s += colpart2[(size_t)b * 256 + slot];
    sums[slot] = s;
    __syncthreads();
    if (slot < 128) {
        float m = sums[slot] * (1.f / NN);
        float var = sums[128 + slot] * (1.f / NN) - m * m;
        float inv = rsqrtf(var + 1e-5f);
        float scl = gamma[slot] * inv;
        sc[slot] = scl;
        sh[slot] = beta[slot] - m * scl;
    }
}

// ---- normalize + ReLU + residual ----
__global__ void final_kernel(const u16* __restrict__ agg, const float* __restrict__ last_x,
                             const float* __restrict__ sc, const float* __restrict__ sh,
                             float* __restrict__ out) {
    int idx = blockIdx.x * blockDim.x + threadIdx.x;   // NN*HD/4 threads
    int c0 = (idx * 4) & 127;
    uint2 a = reinterpret_cast<const uint2*>(agg)[idx];
    float4 lx = reinterpret_cast<const float4*>(last_x)[idx];
    float f0 = __uint_as_float(a.x << 16), f1 = __uint_as_float(a.x & 0xFFFF0000u);
    float f2 = __uint_as_float(a.y << 16), f3 = __uint_as_float(a.y & 0xFFFF0000u);
    float4 o;
    o.x = fmaxf(fmaf(f0, sc[c0 + 0], sh[c0 + 0]), 0.f) + lx.x;
    o.y = fmaxf(fmaf(f1, sc[c0 + 1], sh[c0 + 1]), 0.f) + lx.y;
    o.z = fmaxf(fmaf(f2, sc[c0 + 2], sh[c0 + 2]), 0.f) + lx.z;
    o.w = fmaxf(fmaf(f3, sc[c0 + 3], sh[c0 + 3]), 0.f) + lx.w;
    reinterpret_cast<float4*>(out)[idx] = o;
}

extern "C" void kernel_launch(void* const* d_in, const int* in_sizes, int n_in,
                              void* d_out, int out_size, void* d_ws, size_t ws_size,
                              hipStream_t stream) {
    const float* x      = (const float*)d_in[0];
    const float* last_x = (const float*)d_in[1];
    const int*   edge   = (const int*)d_in[2];   // [2][NE]
    const float* W      = (const float*)d_in[3];
    const float* bias   = (const float*)d_in[4];
    const float* gamma  = (const float*)d_in[5];
    const float* beta   = (const float*)d_in[6];
    float* out = (float*)d_out;

    char* ws = (char*)d_ws;
    size_t p = 0;
    auto take = [&](size_t bytes) { size_t r = p; p += (bytes + 255) & ~255ULL; return r; };
    u32*   counts   = (u32*)(ws + take((size_t)NN * 4));
    u32*   rowptr   = (u32*)(ws + take((size_t)(NN + 1) * 4));
    u32*   cursor   = (u32*)(ws + take((size_t)NN * 4));
    u32*   srclist  = (u32*)(ws + take((size_t)NE * 4));
    float* dinv     = (float*)(ws + take((size_t)NN * 4));
    u16*   xh       = (u16*)(ws + take((size_t)NN * HD * 2));
    u16*   aggX     = (u16*)(ws + take((size_t)NN * HD * 2));
    u16*   aggb     = (u16*)(ws + take((size_t)NN * HD * 2));
    u16*   wf       = (u16*)(ws + take((size_t)HD * HD * 2));
    float* colpart  = (float*)(ws + take((size_t)NBG * 256 * 4));
    float* colpart2 = (float*)(ws + take((size_t)64 * 256 * 4));
    float* sc       = (float*)(ws + take((size_t)HD * 4));
    float* sh       = (float*)(ws + take((size_t)HD * 4));
    u32*   bsum     = (u32*)(ws + take((size_t)NBLK * 4));
    u32*   boff     = (u32*)(ws + take((size_t)NBLK * 4));

    const int* srcp = edge;
    const int* dstp = edge + NE;

    prep_kernel<<<(NN * HD / 4) / 256, 256, 0, stream>>>(x, W, xh, wf, counts, cursor);
    hist_kernel<<<(NE + 255) / 256, 256, 0, stream>>>(dstp, counts);
    scan_bsum<<<NBLK, 256, 0, stream>>>(counts, bsum);
    scan_boff<<<1, 64, 0, stream>>>(bsum, boff);
    scan_final<<<NBLK, 256, 0, stream>>>(counts, boff, rowptr, dinv);
    scatter_kernel<<<8 * SCAT_BPC, 256, 0, stream>>>(srcp, dstp, rowptr, cursor, srclist);
    agg_kernel<<<(NN + 3) / 4, 256, 0, stream>>>(xh, rowptr, srclist, dinv, aggX);
    gemm_kernel<<<NBG, 256, 0, stream>>>(aggX, wf, bias, aggb, colpart);
    reduceA_kernel<<<64, 256, 0, stream>>>(colpart, colpart2);
    stats_kernel<<<1, 256, 0, stream>>>(colpart2, gamma, beta, sc, sh);
    final_kernel<<<(NN * HD / 4) / 256, 256, 0, stream>>>(aggb, last_x, sc, sh, out);
}

// Round 5
// 108.462 us; speedup vs baseline: 2.9798x; 1.4998x over previous
//
#include <hip/hip_runtime.h>
#include <hip/hip_bf16.h>
#include <math.h>

#define NN 50000
#define NE 800000
#define HD 128
#define NBG ((NN + 63) / 64)                        // 782 gemm blocks
#define NB ((NN + 127) >> 7)                        // 391 buckets (128 nodes each)
#define GCAP 3072                                   // max edges per bucket (mean ~2048)
#define PART_EPB 4096
#define PART_NBLK ((NE + PART_EPB - 1) / PART_EPB)  // 196

typedef unsigned int u32;
typedef unsigned short u16;
typedef __attribute__((ext_vector_type(8))) __bf16 bf16x8;
typedef __attribute__((ext_vector_type(4))) float f32x4;

__device__ __forceinline__ u16 f2bf(float f) {
    u32 u = __float_as_uint(f);
    u32 r = u + 0x7FFFu + ((u >> 16) & 1u);   // round-to-nearest-even
    return (u16)(r >> 16);
}
__device__ __forceinline__ void unpack8(uint4 p, float* f) {
    f[0] = __uint_as_float(p.x << 16); f[1] = __uint_as_float(p.x & 0xFFFF0000u);
    f[2] = __uint_as_float(p.y << 16); f[3] = __uint_as_float(p.y & 0xFFFF0000u);
    f[4] = __uint_as_float(p.z << 16); f[5] = __uint_as_float(p.z & 0xFFFF0000u);
    f[6] = __uint_as_float(p.w << 16); f[7] = __uint_as_float(p.w & 0xFFFF0000u);
}

// ---- prep: zero bucket counters, x -> bf16, W -> MFMA fragment layout ----
__global__ void prep_kernel(const float* __restrict__ x, const float* __restrict__ W,
                            u16* __restrict__ xh, u16* __restrict__ wf,
                            u32* __restrict__ bcnt) {
    int idx = blockIdx.x * blockDim.x + threadIdx.x;   // exactly NN*HD/4 threads
    {
        const float4 v = reinterpret_cast<const float4*>(x)[idx];
        u32 lo = (u32)f2bf(v.x) | ((u32)f2bf(v.y) << 16);
        u32 hi = (u32)f2bf(v.z) | ((u32)f2bf(v.w) << 16);
        reinterpret_cast<uint2*>(xh)[idx] = make_uint2(lo, hi);
    }
    if (idx < NB) bcnt[idx] = 0u;
    if (idx < HD * HD) {
        int t  = idx >> 9;           // 0..31
        int c0 = t >> 2, k0 = t & 3;
        int ln = (idx >> 3) & 63;
        int j  = idx & 7;
        int k  = k0 * 32 + (ln >> 4) * 8 + j;
        int c  = (ln & 15) * 8 + c0;
        wf[idx] = f2bf(W[k * HD + c]);
    }
}

// ---- pass 1: radix-partition edges into NB buckets (LDS-staged ranks) ----
__global__ __launch_bounds__(256) void part_kernel(const int* __restrict__ src,
                                                   const int* __restrict__ dst,
                                                   u32* __restrict__ bcnt,
                                                   u32* __restrict__ ebuf) {
    __shared__ u32 lh[NB];
    __shared__ u32 lbase[NB];
    const int tid = threadIdx.x;
    const int e0 = blockIdx.x * PART_EPB;
    for (int i = tid; i < NB; i += 256) lh[i] = 0u;
    __syncthreads();
    #pragma unroll
    for (int j = 0; j < PART_EPB / 256; ++j) {
        int e = e0 + j * 256 + tid;
        if (e < NE) atomicAdd(&lh[dst[e] >> 7], 1u);
    }
    __syncthreads();
    for (int i = tid; i < NB; i += 256) {
        u32 c = lh[i];
        lbase[i] = c ? atomicAdd(&bcnt[i], c) : 0u;
        lh[i] = 0u;                       // reuse as local cursor
    }
    __syncthreads();
    #pragma unroll
    for (int j = 0; j < PART_EPB / 256; ++j) {
        int e = e0 + j * 256 + tid;
        if (e < NE) {
            int d = dst[e], s = src[e];
            int bkt = d >> 7;
            u32 r = atomicAdd(&lh[bkt], 1u);
            u32 pos = lbase[bkt] + r;
            if (pos < GCAP)
                ebuf[(size_t)bkt * GCAP + pos] = (u32)s | ((u32)(d & 127) << 16);
        }
    }
}

// ---- exclusive scan of NB bucket counts (single block) ----
__global__ __launch_bounds__(512) void bscan_kernel(const u32* __restrict__ bcnt,
                                                    u32* __restrict__ bstart) {
    __shared__ u32 wsum[8];
    const int tid = threadIdx.x;
    const int lane = tid & 63, wv = tid >> 6;
    u32 v = (tid < NB) ? bcnt[tid] : 0u;
    u32 inc = v;
    #pragma unroll
    for (int off = 1; off < 64; off <<= 1) {
        u32 y = __shfl_up(inc, off, 64);
        if (lane >= off) inc += y;
    }
    if (lane == 63) wsum[wv] = inc;
    __syncthreads();
    u32 woff = 0;
    #pragma unroll
    for (int j = 0; j < 8; ++j) if (j < wv) woff += wsum[j];
    if (tid < NB) bstart[tid] = woff + inc - v;
}

// ---- pass 2: per-bucket CSR build entirely in LDS; coalesced outputs ----
__global__ __launch_bounds__(256) void bucket_kernel(const u32* __restrict__ ebuf,
                                                     const u32* __restrict__ bcnt,
                                                     const u32* __restrict__ bstart,
                                                     u32* __restrict__ rowptr,
                                                     float* __restrict__ dinv,
                                                     u16* __restrict__ srclist) {
    __shared__ u32 cnt[128], loc[128], cur[128];
    __shared__ u16 stage[GCAP];
    const int tid = threadIdx.x;
    const int b = blockIdx.x;
    const int n0 = b << 7;
    u32 m = bcnt[b]; if (m > GCAP) m = GCAP;
    const u32 base = bstart[b];
    if (tid < 128) { cnt[tid] = 0u; cur[tid] = 0u; }
    __syncthreads();
    for (u32 i = tid; i < m; i += 256)
        atomicAdd(&cnt[ebuf[(size_t)b * GCAP + i] >> 16], 1u);
    __syncthreads();
    if (tid < 64) {                       // exclusive scan of 128 counts, one wave
        u32 c0 = cnt[2 * tid], c1 = cnt[2 * tid + 1];
        u32 s = c0 + c1, inc = s;
        #pragma unroll
        for (int off = 1; off < 64; off <<= 1) {
            u32 y = __shfl_up(inc, off, 64);
            if (tid >= off) inc += y;
        }
        loc[2 * tid]     = inc - s;
        loc[2 * tid + 1] = inc - s + c0;
    }
    __syncthreads();
    if (tid < 128) {
        int node = n0 + tid;
        if (node < NN) {
            rowptr[node] = base + loc[tid];
            dinv[node] = rsqrtf((float)(cnt[tid] + 1u));
        }
    }
    for (u32 i = tid; i < m; i += 256) {
        u32 v = ebuf[(size_t)b * GCAP + i];
        u32 nl = v >> 16;
        u32 r = atomicAdd(&cur[nl], 1u);
        stage[loc[nl] + r] = (u16)(v & 0xFFFFu);
    }
    __syncthreads();
    for (u32 i = tid; i < m; i += 256) srclist[base + i] = stage[i];
    if (b == 0 && tid == 0) rowptr[NN] = NE;
}

// ---- aggregation: one wave per node; 4 edge slots x 16 lanes x 8 features ----
__global__ __launch_bounds__(256) void agg_kernel(
        const u16* __restrict__ xh, const u32* __restrict__ rowptr,
        const u16* __restrict__ srclist, const float* __restrict__ dinv,
        u16* __restrict__ aggX) {
    int wid = (blockIdx.x * blockDim.x + threadIdx.x) >> 6;
    if (wid >= NN) return;
    const int lane = threadIdx.x & 63;
    const int eq = lane >> 4;
    const int fl = lane & 15;
    const int v = wid;
    const float dv = dinv[v];
    float acc[8];
    {
        uint4 sv = reinterpret_cast<const uint4*>(xh + (size_t)v * HD)[fl];
        float f[8]; unpack8(sv, f);
        float s = (eq == 0) ? dv : 0.f;
        #pragma unroll
        for (int j = 0; j < 8; ++j) acc[j] = s * f[j];
    }
    const u32 rs = rowptr[v], re = rowptr[v + 1];
    for (u32 i = rs + eq; i < re; i += 4) {
        u32 u = (u32)srclist[i];
        float du = dinv[u];
        uint4 mu = reinterpret_cast<const uint4*>(xh + (size_t)u * HD)[fl];
        float f[8]; unpack8(mu, f);
        #pragma unroll
        for (int j = 0; j < 8; ++j) acc[j] = fmaf(du, f[j], acc[j]);
    }
    #pragma unroll
    for (int j = 0; j < 8; ++j) {
        acc[j] += __shfl_xor(acc[j], 16, 64);
        acc[j] += __shfl_xor(acc[j], 32, 64);
    }
    if (eq == 0) {
        u32 w[4];
        #pragma unroll
        for (int q = 0; q < 4; ++q) {
            w[q] = (u32)f2bf(dv * acc[2 * q]) | ((u32)f2bf(dv * acc[2 * q + 1]) << 16);
        }
        reinterpret_cast<uint4*>(aggX + (size_t)v * HD)[fl] =
            make_uint4(w[0], w[1], w[2], w[3]);
    }
}

// ---- MFMA GEMM: agg = aggX @ W + b; coalesced uint4 C-stores; BN stats via
// butterfly + per-block partials (NO global atomics) ----
__global__ __launch_bounds__(256) void gemm_kernel(
        const u16* __restrict__ aggX, const u16* __restrict__ wf,
        const float* __restrict__ bias,
        u16* __restrict__ agg, float* __restrict__ colpart) {
    __shared__ float cs_l[128];
    __shared__ float cq_l[128];
    const int tid = threadIdx.x;
    if (tid < 128) { cs_l[tid] = 0.f; cq_l[tid] = 0.f; }
    __syncthreads();

    const int lane = tid & 63, wave = tid >> 6;
    const int r0 = blockIdx.x * 64 + wave * 16;
    const int l15 = lane & 15, rgrp = lane >> 4;
    const int rrow = r0 + l15;

    bf16x8 a[4];
    #pragma unroll
    for (int k0 = 0; k0 < 4; ++k0) {
        if (rrow < NN)
            a[k0] = *reinterpret_cast<const bf16x8*>(aggX + (size_t)rrow * HD + k0 * 32 + rgrp * 8);
        else
            a[k0] = bf16x8{};
    }

    f32x4 acc[8];
    #pragma unroll
    for (int c0 = 0; c0 < 8; ++c0) acc[c0] = f32x4{0.f, 0.f, 0.f, 0.f};
    #pragma unroll
    for (int c0 = 0; c0 < 8; ++c0) {
        #pragma unroll
        for (int k0 = 0; k0 < 4; ++k0) {
            bf16x8 b = *reinterpret_cast<const bf16x8*>(wf + ((c0 * 4 + k0) * 64 + lane) * 8);
            acc[c0] = __builtin_amdgcn_mfma_f32_16x16x32_bf16(a[k0], b, acc[c0], 0, 0, 0);
        }
    }

    float4 b4a = *reinterpret_cast<const float4*>(bias + l15 * 8);
    float4 b4b = *reinterpret_cast<const float4*>(bias + l15 * 8 + 4);
    const float bcol[8] = {b4a.x, b4a.y, b4a.z, b4a.w, b4b.x, b4b.y, b4b.z, b4b.w};

    float cp[8] = {}, cq[8] = {};
    #pragma unroll
    for (int reg = 0; reg < 4; ++reg) {
        int row = r0 + rgrp * 4 + reg;
        float v[8];
        #pragma unroll
        for (int c0 = 0; c0 < 8; ++c0) v[c0] = acc[c0][reg] + bcol[c0];
        if (row < NN) {
            u32 w4[4];
            #pragma unroll
            for (int q = 0; q < 4; ++q)
                w4[q] = (u32)f2bf(v[2 * q]) | ((u32)f2bf(v[2 * q + 1]) << 16);
            *reinterpret_cast<uint4*>(agg + (size_t)row * HD + l15 * 8) =
                make_uint4(w4[0], w4[1], w4[2], w4[3]);
            #pragma unroll
            for (int c0 = 0; c0 < 8; ++c0) { cp[c0] += v[c0]; cq[c0] += v[c0] * v[c0]; }
        }
    }
    #pragma unroll
    for (int c0 = 0; c0 < 8; ++c0) {
        cp[c0] += __shfl_xor(cp[c0], 16, 64); cp[c0] += __shfl_xor(cp[c0], 32, 64);
        cq[c0] += __shfl_xor(cq[c0], 16, 64); cq[c0] += __shfl_xor(cq[c0], 32, 64);
    }
    if (rgrp == 0) {
        #pragma unroll
        for (int c0 = 0; c0 < 8; ++c0) {
            atomicAdd(&cs_l[l15 * 8 + c0], cp[c0]);
            atomicAdd(&cq_l[l15 * 8 + c0], cq[c0]);
        }
    }
    __syncthreads();
    if (tid < 128) {
        colpart[(size_t)blockIdx.x * 256 + tid] = cs_l[tid];
        colpart[(size_t)blockIdx.x * 256 + 128 + tid] = cq_l[tid];
    }
}

// ---- stats reduce stage A: 782 partial rows -> 64 ----
__global__ __launch_bounds__(256) void reduceA_kernel(const float* __restrict__ colpart,
                                                      float* __restrict__ colpart2) {
    int slot = threadIdx.x;
    float s = 0.f;
    for (int b = blockIdx.x; b < NBG; b += 64) s += colpart[(size_t)b * 256 + slot];
    colpart2[(size_t)blockIdx.x * 256 + slot] = s;
}

// ---- stats finalize: 64 rows -> mean/var -> scale/shift ----
__global__ __launch_bounds__(256) void stats_kernel(const float* __restrict__ colpart2,
                                                    const float* __restrict__ gamma,
                                                    const float* __restrict__ beta,
                                                    float* __restrict__ sc, float* __restrict__ sh) {
    __shared__ float sums[256];
    int slot = threadIdx.x;
    float s = 0.f;
    for (int b = 0; b < 64; ++b) s += colpart2[(size_t)b * 256 + slot];
    sums[slot] = s;
    __syncthreads();
    if (slot < 128) {
        float m = sums[slot] * (1.f / NN);
        float var = sums[128 + slot] * (1.f / NN) - m * m;
        float inv = rsqrtf(var + 1e-5f);
        float scl = gamma[slot] * inv;
        sc[slot] = scl;
        sh[slot] = beta[slot] - m * scl;
    }
}

// ---- normalize + ReLU + residual ----
__global__ void final_kernel(const u16* __restrict__ agg, const float* __restrict__ last_x,
                             const float* __restrict__ sc, const float* __restrict__ sh,
                             float* __restrict__ out) {
    int idx = blockIdx.x * blockDim.x + threadIdx.x;   // NN*HD/4 threads
    int c0 = (idx * 4) & 127;
    uint2 a = reinterpret_cast<const uint2*>(agg)[idx];
    float4 lx = reinterpret_cast<const float4*>(last_x)[idx];
    float f0 = __uint_as_float(a.x << 16), f1 = __uint_as_float(a.x & 0xFFFF0000u);
    float f2 = __uint_as_float(a.y << 16), f3 = __uint_as_float(a.y & 0xFFFF0000u);
    float4 o;
    o.x = fmaxf(fmaf(f0, sc[c0 + 0], sh[c0 + 0]), 0.f) + lx.x;
    o.y = fmaxf(fmaf(f1, sc[c0 + 1], sh[c0 + 1]), 0.f) + lx.y;
    o.z = fmaxf(fmaf(f2, sc[c0 + 2], sh[c0 + 2]), 0.f) + lx.z;
    o.w = fmaxf(fmaf(f3, sc[c0 + 3], sh[c0 + 3]), 0.f) + lx.w;
    reinterpret_cast<float4*>(out)[idx] = o;
}

extern "C" void kernel_launch(void* const* d_in, const int* in_sizes, int n_in,
                              void* d_out, int out_size, void* d_ws, size_t ws_size,
                              hipStream_t stream) {
    const float* x      = (const float*)d_in[0];
    const float* last_x = (const float*)d_in[1];
    const int*   edge   = (const int*)d_in[2];   // [2][NE]
    const float* W      = (const float*)d_in[3];
    const float* bias   = (const float*)d_in[4];
    const float* gamma  = (const float*)d_in[5];
    const float* beta   = (const float*)d_in[6];
    float* out = (float*)d_out;

    char* ws = (char*)d_ws;
    size_t p = 0;
    auto take = [&](size_t bytes) { size_t r = p; p += (bytes + 255) & ~255ULL; return r; };
    u32*   bcnt     = (u32*)(ws + take((size_t)NB * 4));
    u32*   bstart   = (u32*)(ws + take((size_t)NB * 4));
    u32*   ebuf     = (u32*)(ws + take((size_t)NB * GCAP * 4));
    u32*   rowptr   = (u32*)(ws + take((size_t)(NN + 1) * 4));
    u16*   srclist  = (u16*)(ws + take((size_t)NE * 2));
    float* dinv     = (float*)(ws + take((size_t)NN * 4));
    u16*   xh       = (u16*)(ws + take((size_t)NN * HD * 2));
    u16*   aggX     = (u16*)(ws + take((size_t)NN * HD * 2));
    u16*   aggb     = (u16*)(ws + take((size_t)NN * HD * 2));
    u16*   wf       = (u16*)(ws + take((size_t)HD * HD * 2));
    float* colpart  = (float*)(ws + take((size_t)NBG * 256 * 4));
    float* colpart2 = (float*)(ws + take((size_t)64 * 256 * 4));
    float* sc       = (float*)(ws + take((size_t)HD * 4));
    float* sh       = (float*)(ws + take((size_t)HD * 4));

    const int* srcp = edge;
    const int* dstp = edge + NE;

    prep_kernel<<<(NN * HD / 4) / 256, 256, 0, stream>>>(x, W, xh, wf, bcnt);
    part_kernel<<<PART_NBLK, 256, 0, stream>>>(srcp, dstp, bcnt, ebuf);
    bscan_kernel<<<1, 512, 0, stream>>>(bcnt, bstart);
    bucket_kernel<<<NB, 256, 0, stream>>>(ebuf, bcnt, bstart, rowptr, dinv, srclist);
    agg_kernel<<<(NN + 3) / 4, 256, 0, stream>>>(xh, rowptr, srclist, dinv, aggX);
    gemm_kernel<<<NBG, 256, 0, stream>>>(aggX, wf, bias, aggb, colpart);
    reduceA_kernel<<<64, 256, 0, stream>>>(colpart, colpart2);
    stats_kernel<<<1, 256, 0, stream>>>(colpart2, gamma, beta, sc, sh);
    final_kernel<<<(NN * HD / 4) / 256, 256, 0, stream>>>(aggb, last_x, sc, sh, out);
}